// Round 12
// baseline (460.927 us; speedup 1.0000x reference)
//
#include <hip/hip_runtime.h>
#include <stdint.h>

typedef unsigned short u16;
typedef uint32_t u32;
typedef short s16x8 __attribute__((ext_vector_type(8)));
typedef float fx16 __attribute__((ext_vector_type(16)));

#define B_   256
#define H_   1024
#define BH_  (B_ * H_)                  // 262144
#define WPE  ((size_t)2 * 4096 * 2048)  // W pack elems
#define XPE  ((size_t)15 * BH_)
#define HPE  ((size_t)32 * BH_)
#define NTH  16                         // K-steps per half (BK=64)
#define GPLANE ((size_t)B_ * 4096)      // partial plane f32 elems (4 MB)

// mode: 0 = seg0 -> f32 partial (+flag if layer1)
//       1 = seg0 + gates (par==0 cells: no seg1 exists)
//       2 = seg1 + read partial (+poll if layer1) + gates
struct StageEx {
    signed char node[16], par[16], layer[16], mode[16], slot[16];
    int cnt;
};

__device__ __forceinline__ u16 bf16_rn(float x) {
    union { float f; u32 u; } v; v.f = x;
    return (u16)((v.u + 0x7FFFu + ((v.u >> 16) & 1u)) >> 16);
}
__device__ __forceinline__ float sigf(float x) {
    return __builtin_amdgcn_rcpf(1.0f + __expf(-x));
}
__device__ __forceinline__ float tanh_f(float x) {
    return 1.0f - 2.0f * __builtin_amdgcn_rcpf(1.0f + __expf(2.0f * x));
}

// ---------------------------------------------------------------------------
__global__ __launch_bounds__(256)
void pack_weights(const float* __restrict__ Wih, const float* __restrict__ Whh,
                  u16* __restrict__ wp)
{
    const int gt = blockIdx.x * 256 + threadIdx.x;
    const int w = gt >> 6, lane = gt & 63;
    const int k16 = w & 127, cg = (w >> 7) & 31, gate = (w >> 12) & 3, layer = w >> 14;
    const int row = gate * 1024 + cg * 32 + (lane & 31);
    const int k = k16 * 16 + (lane >> 5) * 8;
    const float* src = (k < 1024)
        ? Wih + ((size_t)layer * 4096 + row) * 1024 + k
        : Whh + ((size_t)layer * 4096 + row) * 1024 + (k - 1024);
    const float4 v0 = *(const float4*)src;
    const float4 v1 = *(const float4*)(src + 4);
    const float a[8] = {v0.x, v0.y, v0.z, v0.w, v1.x, v1.y, v1.z, v1.w};
    union { u16 s[8]; uint4 v; } hi;
    #pragma unroll
    for (int e = 0; e < 8; ++e) hi.s[e] = bf16_rn(a[e]);
    *(uint4*)(wp + (size_t)w * 512 + (size_t)lane * 8) = hi.v;
}

__global__ __launch_bounds__(256)
void pack_x(const float* __restrict__ input, const float* __restrict__ bridge,
            u16* __restrict__ xp)
{
    const int gt = blockIdx.x * 256 + threadIdx.x;
    const int w = gt >> 6, lane = gt & 63;
    const int k16 = w & 63, btile = (w >> 6) & 7, n1 = w >> 9;
    const int b = btile * 32 + (lane & 31);
    const int k = k16 * 16 + (lane >> 5) * 8;
    const float* src = (k < 512)
        ? input  + ((size_t)n1 * 256 + b) * 512 + k
        : bridge + ((size_t)n1 * 256 + b) * 512 + (k - 512);
    const float4 v0 = *(const float4*)src;
    const float4 v1 = *(const float4*)(src + 4);
    const float a[8] = {v0.x, v0.y, v0.z, v0.w, v1.x, v1.y, v1.z, v1.w};
    union { u16 s[8]; uint4 v; } hi;
    #pragma unroll
    for (int e = 0; e < 8; ++e) hi.s[e] = bf16_rn(a[e]);
    *(uint4*)(xp + (size_t)w * 512 + (size_t)lane * 8) = hi.v;
}

__global__ __launch_bounds__(256)
void bias_sum_k(const float* __restrict__ bih, const float* __restrict__ bhh,
                float* __restrict__ bs)
{
    const int i = blockIdx.x * 256 + threadIdx.x;
    if (i < 8192) bs[i] = bih[i] + bhh[i];
}

// ---------------------------------------------------------------------------
// Half-K cell block. 512 thr / 8 waves. BM=256 (wave wv: rows wv*32..+31),
// BN=128 (4 gates x 32 hh; hhblk 0..31; XCD = u%8 stable).
// K = 16 steps x 64 (one segment). LDS 48 KB single-buffer (A 32K + W 16K),
// r8-proven sync-pair loop. Producer/consumer within a dispatch via padded
// agent-scope flags (l1 cells only); producers listed first in bid order,
// <=512 blocks per dispatch at 2/CU -> all co-resident, poll-at-end only.
// ---------------------------------------------------------------------------
__global__ __launch_bounds__(512, 4)
void cell_half(const u16* __restrict__ wp, const u16* __restrict__ xp,
               u16* __restrict__ hp, float* __restrict__ c_buf,
               const float* __restrict__ bsum, float* __restrict__ out,
               float* __restrict__ gpart, int* __restrict__ flags,
               StageEx st)
{
    __shared__ u16 SM[24576];            // A: 0..16383, W: 16384..24575 (48 KB)

    const int bid  = blockIdx.x;
    const int item = bid >> 5;
    const int u    = bid & 31;
    const int hhblk = 4 * (u & 7) + (u >> 3);
    const int node  = st.node[item], par = st.par[item];
    const int layer = st.layer[item], mode = st.mode[item], slot = st.slot[item];
    const int seg   = (mode == 2) ? 1 : 0;

    const int tid = threadIdx.x, wv = tid >> 6, lane = tid & 63;
    const int tq  = tid >> 8;
    const int kks = (tid >> 6) & 3;
    const int e8  = (tid & 63) * 8;

    // A base for this segment
    const u16* Ab;
    if (mode == 2) Ab = hp + (size_t)(par * 2 + layer) * BH_;
    else           Ab = layer ? hp + (size_t)(node * 2) * BH_
                              : xp + (size_t)(node - 1) * BH_;

    size_t wsg[2];
    #pragma unroll
    for (int i = 0; i < 2; ++i)
        wsg[i] = (size_t)((layer * 4 + (2 * i + tq)) * 32 + hhblk) * 65536
               + (size_t)seg * 32768 + (size_t)kks * 512 + e8;

    fx16 acc[4];
    #pragma unroll
    for (int g = 0; g < 4; ++g)
        #pragma unroll
        for (int r = 0; r < 16; ++r) acc[g][r] = 0.0f;

    #pragma unroll 1
    for (int t = 0; t < NTH; ++t) {
        // ---- stage 48 KB: A 4 instr/thread (bt = 2i+tq), W 2 instr/thread
        const size_t ab = ((size_t)t * 4 + kks) * 512 + e8;
        #pragma unroll
        for (int i = 0; i < 4; ++i) {
            __builtin_amdgcn_global_load_lds(
                (const __attribute__((address_space(1))) void*)
                    (Ab + (size_t)(2 * i + tq) * 32768 + ab),
                (__attribute__((address_space(3))) void*)
                    (SM + i * 4096 + tid * 8),
                16, 0, 0);
        }
        #pragma unroll
        for (int i = 0; i < 2; ++i) {
            __builtin_amdgcn_global_load_lds(
                (const __attribute__((address_space(1))) void*)
                    (wp + wsg[i] + (size_t)t * 2048),
                (__attribute__((address_space(3))) void*)
                    (SM + 16384 + i * 4096 + tid * 8),
                16, 0, 0);
        }
        __syncthreads();
        #pragma unroll
        for (int kk = 0; kk < 4; ++kk) {
            const s16x8 a_ = *(const s16x8*)(SM + wv * 2048 + kk * 512 + lane * 8);
            #pragma unroll
            for (int g = 0; g < 4; ++g) {
                const s16x8 w_ = *(const s16x8*)
                    (SM + 16384 + g * 2048 + kk * 512 + lane * 8);
                acc[g] = __builtin_amdgcn_mfma_f32_32x32x16_bf16(
                    a_, w_, acc[g], 0, 0, 0);
            }
        }
        __syncthreads();
    }

    // C/D layout: col = lane&31, row = (r&3)+8*(r>>2)+4*(lane>>5)
    const int col  = lane & 31;
    const int colg = hhblk * 32 + col;

    if (mode == 0) {
        // ---- write f32 partial; flag if same-dispatch consumer (layer 1)
        float* gp = gpart + (size_t)slot * GPLANE;
        #pragma unroll
        for (int r = 0; r < 16; ++r) {
            const int rl  = 4 * (lane >> 5) + (r & 3) + 8 * (r >> 2);
            const size_t row = (size_t)(wv * 32 + rl) * 4096;
            #pragma unroll
            for (int g = 0; g < 4; ++g)
                gp[row + g * 1024 + colg] = acc[g][r];
        }
        if (layer == 1) {
            __syncthreads();   // all waves' stores retired (vmcnt 0)
            if (tid == 0)
                __hip_atomic_store(flags + (node * 32 + u) * 32, 1,
                                   __ATOMIC_RELEASE, __HIP_MEMORY_SCOPE_AGENT);
        }
        return;
    }

    const float* pp = (mode == 2) ? gpart + (size_t)slot * GPLANE : nullptr;
    if (mode == 2 && layer == 1) {
        if (tid == 0) {
            while (__hip_atomic_load(flags + (node * 32 + u) * 32,
                                     __ATOMIC_ACQUIRE,
                                     __HIP_MEMORY_SCOPE_AGENT) < 1) {
                __builtin_amdgcn_s_sleep(4);
            }
        }
        __syncthreads();
    }

    // ---- fused gates epilogue
    float bs4[4];
    #pragma unroll
    for (int g = 0; g < 4; ++g)
        bs4[g] = bsum[layer * 4096 + g * 1024 + colg];

    const float* cpar = c_buf + (size_t)(par * 2 + layer) * BH_ + colg;
    float*       cnew = c_buf + (size_t)(node * 2 + layer) * BH_ + colg;
    float*       outp = out + (size_t)(node - 1) * BH_ + colg;
    u16*         hpn  = hp + (size_t)(node * 2 + layer) * BH_;

    u32* hq = (u32*)(&SM[0]) + wv * 1056;   // per-wave 32x33 u32 scratch

    #pragma unroll
    for (int r = 0; r < 16; ++r) {
        const int rl = 4 * (lane >> 5) + (r & 3) + 8 * (r >> 2);
        const size_t row = (size_t)(wv * 32 + rl) * 1024;
        float gv[4];
        #pragma unroll
        for (int g = 0; g < 4; ++g) {
            gv[g] = acc[g][r] + bs4[g];
            if (mode == 2)
                gv[g] += pp[(size_t)(wv * 32 + rl) * 4096 + g * 1024 + colg];
        }
        const float cp = cpar[row];
        const float cn = sigf(gv[1]) * cp + sigf(gv[0]) * tanh_f(gv[2]);
        const float hn = sigf(gv[3]) * tanh_f(cn);
        cnew[row] = cn;
        if (layer == 1) outp[row] = hn;
        hq[rl * 33 + col] = (u32)bf16_rn(hn);
    }

    // ---- transpose h (wave-local) into packed A-frag chunks
    #pragma unroll
    for (int q = 0; q < 2; ++q) {
        const int k16h = hhblk * 2 + q;
        union { u16 s[8]; uint4 v; } pk;
        #pragma unroll
        for (int e = 0; e < 8; ++e)
            pk.s[e] = (u16)hq[(lane & 31) * 33 + q * 16 + (lane >> 5) * 8 + e];
        *(uint4*)(hpn + ((size_t)wv * 64 + k16h) * 512 + lane * 8) = pk.v;
    }
}

// ---------------------------------------------------------------------------
extern "C" void kernel_launch(void* const* d_in, const int* in_sizes, int n_in,
                              void* d_out, int out_size, void* d_ws, size_t ws_size,
                              hipStream_t stream)
{
    const float* input  = (const float*)d_in[0];
    const float* bridge = (const float*)d_in[1];
    const float* Wih    = (const float*)d_in[2];
    const float* Whh    = (const float*)d_in[3];
    const float* bih    = (const float*)d_in[4];
    const float* bhh    = (const float*)d_in[5];
    float* out = (float*)d_out;

    u16* wp = (u16*)d_ws;                      // 33.5 MB
    u16* xp = wp + WPE;                        // 7.9 MB
    u16* hp = xp + XPE;                        // 16.8 MB
    float* c_buf = (float*)(hp + HPE);         // 33.5 MB
    float* bsum  = c_buf + HPE;                // 32 KB
    float* gpart = bsum + 8192;                // 19 x 4 MB = 76 MB
    int*   flags = (int*)(gpart + (size_t)19 * GPLANE);  // 64 KB

    hipMemsetAsync(hp, 0, (size_t)2 * BH_ * sizeof(u16), stream);
    hipMemsetAsync(c_buf, 0, (size_t)2 * BH_ * sizeof(float), stream);
    hipMemsetAsync(flags, 0, 16384 * sizeof(int), stream);

    bias_sum_k<<<32, 256, 0, stream>>>(bih, bhh, bsum);
    pack_weights<<<8192, 256, 0, stream>>>(Wih, Whh, wp);
    pack_x<<<1920, 256, 0, stream>>>(input, bridge, xp);

    // Slots: layer-0 partial of node n -> n-1 (persist from S0); layer-1 -> 15..18.
    // Producers (mode 0) listed BEFORE consumers (mode 2) in every stage.
    static const StageEx S[7] = {
        // S0: all layer-0 seg0; node 1 fused (par==0 -> no seg1 exists)
        { {1,2,3,4,5,6,7,8,9,10,11,12,13,14,15},
          {0,1,2,3,1,5,6,1,8,9,10,8,12,13,14},
          {0,0,0,0,0,0,0,0,0,0,0,0,0,0,0},
          {1,0,0,0,0,0,0,0,0,0,0,0,0,0,0},
          {0,1,2,3,4,5,6,7,8,9,10,11,12,13,14}, 15 },
        // S1 (T2): (1,1) seg0+gates; (2,0),(5,0),(8,0) seg1+gates
        { {1,2,5,8}, {0,1,1,1}, {1,0,0,0}, {1,2,2,2}, {0,1,4,7}, 4 },
        // S2 (T3): l1 pairs for 2,5,8; l0 seg1 for 3,6,9,12
        { {2,5,8, 2,5,8, 3,6,9,12},
          {1,1,1, 1,1,1, 2,5,8,8},
          {1,1,1, 1,1,1, 0,0,0,0},
          {0,0,0, 2,2,2, 2,2,2,2},
          {15,16,17, 15,16,17, 2,5,8,11}, 10 },
        // S3 (T4): l1 pairs 3,6,9,12; l0 seg1 4,7,10,13
        { {3,6,9,12, 3,6,9,12, 4,7,10,13},
          {2,5,8,8,  2,5,8,8,  3,6,9,12},
          {1,1,1,1,  1,1,1,1,  0,0,0,0},
          {0,0,0,0,  2,2,2,2,  2,2,2,2},
          {15,16,17,18, 15,16,17,18, 3,6,9,12}, 12 },
        // S4 (T5): l1 pairs 4,7,10,13; l0 seg1 11,14
        { {4,7,10,13, 4,7,10,13, 11,14},
          {3,6,9,12,  3,6,9,12,  10,13},
          {1,1,1,1,   1,1,1,1,   0,0},
          {0,0,0,0,   2,2,2,2,   2,2},
          {15,16,17,18, 15,16,17,18, 10,13}, 10 },
        // S5 (T6): l1 pairs 11,14; l0 seg1 15
        { {11,14, 11,14, 15},
          {10,13, 10,13, 14},
          {1,1,   1,1,   0},
          {0,0,   2,2,   2},
          {15,16, 15,16, 14}, 5 },
        // S6 (T7): l1 pair 15
        { {15,15}, {14,14}, {1,1}, {0,2}, {15,15}, 2 },
    };

    for (int s = 0; s < 7; ++s) {
        cell_half<<<dim3(S[s].cnt * 32), 512, 0, stream>>>(
            wp, xp, hp, c_buf, bsum, out, gpart, flags, S[s]);
    }
}

// Round 13
// 268.819 us; speedup vs baseline: 1.7146x; 1.7146x over previous
//
#include <hip/hip_runtime.h>
#include <stdint.h>

typedef unsigned short u16;
typedef uint32_t u32;
typedef short s16x8 __attribute__((ext_vector_type(8)));
typedef float fx16 __attribute__((ext_vector_type(16)));

#define B_   256
#define H_   1024
#define BH_  (B_ * H_)                  // 262144
#define WPE  ((size_t)2 * 4096 * 2048)  // W pack elems
#define XPE  ((size_t)15 * BH_)
#define HPE  ((size_t)32 * BH_)
#define NT   16                         // K-steps (BK=128)

struct Stage { int node[8]; int par[8]; int layer[8]; int cnt; };

__device__ __forceinline__ u16 bf16_rn(float x) {
    union { float f; u32 u; } v; v.f = x;
    return (u16)((v.u + 0x7FFFu + ((v.u >> 16) & 1u)) >> 16);
}
__device__ __forceinline__ float sigf(float x) {
    return __builtin_amdgcn_rcpf(1.0f + __expf(-x));
}
__device__ __forceinline__ float tanh_f(float x) {
    return 1.0f - 2.0f * __builtin_amdgcn_rcpf(1.0f + __expf(2.0f * x));
}

// ---------------------------------------------------------------------------
// Pack W into MFMA-B fragment order, bf16. Chunk w = ((layer*4+gate)*32+cg)*128+k16;
// lane l -> W[gate*1024+cg*32+(l&31)][k16*16+(l>>5)*8+e].
// ---------------------------------------------------------------------------
__global__ __launch_bounds__(256)
void pack_weights(const float* __restrict__ Wih, const float* __restrict__ Whh,
                  u16* __restrict__ wp)
{
    const int gt = blockIdx.x * 256 + threadIdx.x;
    const int w = gt >> 6, lane = gt & 63;
    const int k16 = w & 127, cg = (w >> 7) & 31, gate = (w >> 12) & 3, layer = w >> 14;
    const int row = gate * 1024 + cg * 32 + (lane & 31);
    const int k = k16 * 16 + (lane >> 5) * 8;
    const float* src = (k < 1024)
        ? Wih + ((size_t)layer * 4096 + row) * 1024 + k
        : Whh + ((size_t)layer * 4096 + row) * 1024 + (k - 1024);
    const float4 v0 = *(const float4*)src;
    const float4 v1 = *(const float4*)(src + 4);
    const float a[8] = {v0.x, v0.y, v0.z, v0.w, v1.x, v1.y, v1.z, v1.w};
    union { u16 s[8]; uint4 v; } hi;
    #pragma unroll
    for (int e = 0; e < 8; ++e) hi.s[e] = bf16_rn(a[e]);
    *(uint4*)(wp + (size_t)w * 512 + (size_t)lane * 8) = hi.v;
}

__global__ __launch_bounds__(256)
void pack_x(const float* __restrict__ input, const float* __restrict__ bridge,
            u16* __restrict__ xp)
{
    const int gt = blockIdx.x * 256 + threadIdx.x;
    const int w = gt >> 6, lane = gt & 63;
    const int k16 = w & 63, btile = (w >> 6) & 7, n1 = w >> 9;
    const int b = btile * 32 + (lane & 31);
    const int k = k16 * 16 + (lane >> 5) * 8;
    const float* src = (k < 512)
        ? input  + ((size_t)n1 * 256 + b) * 512 + k
        : bridge + ((size_t)n1 * 256 + b) * 512 + (k - 512);
    const float4 v0 = *(const float4*)src;
    const float4 v1 = *(const float4*)(src + 4);
    const float a[8] = {v0.x, v0.y, v0.z, v0.w, v1.x, v1.y, v1.z, v1.w};
    union { u16 s[8]; uint4 v; } hi;
    #pragma unroll
    for (int e = 0; e < 8; ++e) hi.s[e] = bf16_rn(a[e]);
    *(uint4*)(xp + (size_t)w * 512 + (size_t)lane * 8) = hi.v;
}

__global__ __launch_bounds__(256)
void bias_sum_k(const float* __restrict__ bih, const float* __restrict__ bhh,
                float* __restrict__ bs)
{
    const int i = blockIdx.x * 256 + threadIdx.x;
    if (i < 8192) bs[i] = bih[i] + bhh[i];
}

// ---------------------------------------------------------------------------
// Fused cell, r8 structure with BK=128 (16 K-steps instead of 32).
// Block = 256 thr (4 waves), tile M=128 x N=128 (4 gates x 32 hh).
// Per step: stage A 32KB + W 32KB (16 x global_load_lds/thread, single
// buffer) -> sync -> 32 ds_read + 32 MFMA per wave -> sync. Halved step
// count amortizes the per-step exposed round-trip over 2x compute.
// LDS 64 KB -> 2 blocks/CU. Cells with par==0 skip seg1 (parent h == 0):
// only 8 steps. 64 blocks/cell; XCD-stable hhblk grouping.
// ---------------------------------------------------------------------------
__global__ __launch_bounds__(256, 2)
void cell_fused(const u16* __restrict__ wp, const u16* __restrict__ xp,
                u16* __restrict__ hp, float* __restrict__ c_buf,
                const float* __restrict__ bsum, float* __restrict__ out,
                Stage st)
{
    __shared__ __align__(16) char SMEM[65536];
    u16*   AL   = (u16*)SMEM;            // [btl(4)][kkq(8)][512] = 32 KB
    u16*   WL   = AL + 16384;            // [g(4)][kkq(8)][512]   = 32 KB
    float* gbuf = (float*)SMEM;          // [64][129] f32 (epilogue overlay)
    u16*   tbuf = (u16*)(SMEM + 33024);  // [64][33] u16 (epilogue overlay)

    const int u = blockIdx.x;
    const int hhblk = 4 * (u & 7) + ((u >> 3) & 3);   // 0..31, XCD-stable
    const int v = u >> 5;
    const int cnt = st.cnt;
    const int cell = v % cnt;
    const int mblk = v / cnt;                          // 0..1
    const int node = st.node[cell], par = st.par[cell], layer = st.layer[cell];
    const int tid = threadIdx.x, wv = tid >> 6, lane = tid & 63;
    const int mw = wv >> 1, nw = wv & 1;
    const int tg = tid >> 6;                           // 0..3
    const int tl8 = (tid & 63) * 8;

    // A segment bases (seg0 = K 0..1023, seg1 = K 1024..2047)
    const u16 *A0, *A1;
    if (layer == 0) {
        A0 = xp + (size_t)(node - 1) * BH_;
        A1 = hp + (size_t)(par * 2 + 0) * BH_;
    } else {
        A0 = hp + (size_t)(node * 2 + 0) * BH_;
        A1 = hp + (size_t)(par * 2 + 1) * BH_;
    }
    // W chunk-run base per gate (chunk = k16 in 0..127, 512 elems each)
    size_t wbase[4];
    #pragma unroll
    for (int g = 0; g < 4; ++g)
        wbase[g] = (size_t)((layer * 4 + g) * 32 + hhblk) * 65536 + (size_t)tl8;

    // par==0 -> parent h is all zeros: seg1 MFMAs add exact 0; skip them.
    const int nsteps = (par == 0) ? (NT / 2) : NT;

    fx16 acc[2][2];
    #pragma unroll
    for (int m = 0; m < 2; ++m)
        #pragma unroll
        for (int n = 0; n < 2; ++n)
            #pragma unroll
            for (int r = 0; r < 16; ++r) acc[m][n][r] = 0.0f;

    #pragma unroll 1
    for (int t = 0; t < nsteps; ++t) {
        // ---- stage A 32KB: instr i -> chunk c = i*4+tg; btl=c>>3, kkq=c&7
        const u16* As = (t < 8) ? A0 : A1;
        const int k16s = (t & 7) * 8;                 // k16 base within segment
        #pragma unroll
        for (int i = 0; i < 8; ++i) {
            const int c = i * 4 + tg;
            __builtin_amdgcn_global_load_lds(
                (const __attribute__((address_space(1))) void*)
                    (As + ((size_t)(mblk * 4 + (c >> 3)) * 64
                           + k16s + (c & 7)) * 512 + tl8),
                (__attribute__((address_space(3))) void*)
                    (AL + c * 512 + tl8),
                16, 0, 0);
        }
        // ---- stage W 32KB: instr i -> chunk c = i*4+tg; g=c>>3, kkq=c&7
        #pragma unroll
        for (int i = 0; i < 8; ++i) {
            const int c = i * 4 + tg;
            __builtin_amdgcn_global_load_lds(
                (const __attribute__((address_space(1))) void*)
                    (wp + wbase[c >> 3] + (size_t)(t * 8 + (c & 7)) * 512),
                (__attribute__((address_space(3))) void*)
                    (WL + c * 512 + tl8),
                16, 0, 0);
        }
        __syncthreads();
        // ---- compute: 8 kk x (2 A + 2 W reads, 4 MFMA) per wave
        #pragma unroll
        for (int kk = 0; kk < 8; ++kk) {
            s16x8 a[2], w[2];
            #pragma unroll
            for (int m = 0; m < 2; ++m)
                a[m] = *(const s16x8*)(AL + ((mw * 2 + m) * 8 + kk) * 512 + lane * 8);
            #pragma unroll
            for (int n = 0; n < 2; ++n)
                w[n] = *(const s16x8*)(WL + ((nw * 2 + n) * 8 + kk) * 512 + lane * 8);
            #pragma unroll
            for (int m = 0; m < 2; ++m)
                #pragma unroll
                for (int n = 0; n < 2; ++n)
                    acc[m][n] = __builtin_amdgcn_mfma_f32_32x32x16_bf16(
                        a[m], w[n], acc[m][n], 0, 0, 0);
        }
        __syncthreads();
    }

    // ---- fused epilogue, two row-passes (p = mw of producing waves)
    const int hhl  = tid & 31;
    const int colg = hhblk * 32 + hhl;
    float bs4[4];
    #pragma unroll
    for (int g = 0; g < 4; ++g)
        bs4[g] = bsum[layer * 4096 + g * 1024 + colg];

    const float* cpar = c_buf + (size_t)(par * 2 + layer) * BH_ + colg;
    float*       cnew = c_buf + (size_t)(node * 2 + layer) * BH_ + colg;
    float*       outp = out + (size_t)(node - 1) * BH_ + colg;
    u16*         hpn  = hp + (size_t)(node * 2 + layer) * BH_;

    #pragma unroll
    for (int p = 0; p < 2; ++p) {
        __syncthreads();
        if (mw == p) {
            // C/D layout: col = lane&31, row = (r&3)+8*(r>>2)+4*(lane>>5)
            #pragma unroll
            for (int m = 0; m < 2; ++m) {
                #pragma unroll
                for (int n = 0; n < 2; ++n) {
                    const int col = (nw * 2 + n) * 32 + (lane & 31);
                    #pragma unroll
                    for (int r = 0; r < 16; ++r) {
                        const int row_l = m * 32 + 4 * (lane >> 5)
                                        + (r & 3) + 8 * (r >> 2);
                        gbuf[row_l * 129 + col] = acc[m][n][r];
                    }
                }
            }
        }
        __syncthreads();
        // gate math: 8 rows/thread-group x 32 hh
        #pragma unroll
        for (int e = 0; e < 8; ++e) {
            const int row_l = e * 8 + (tid >> 5);
            const size_t grow = (size_t)(mblk * 128 + p * 64 + row_l) * 1024;
            const float gi = gbuf[row_l * 129 + 0  * 32 + hhl] + bs4[0];
            const float gf = gbuf[row_l * 129 + 1  * 32 + hhl] + bs4[1];
            const float gg = gbuf[row_l * 129 + 2  * 32 + hhl] + bs4[2];
            const float go = gbuf[row_l * 129 + 3  * 32 + hhl] + bs4[3];
            const float cp = cpar[grow];
            const float cn = sigf(gf) * cp + sigf(gi) * tanh_f(gg);
            const float hn = sigf(go) * tanh_f(cn);
            cnew[grow] = cn;
            if (layer == 1) outp[grow] = hn;
            tbuf[row_l * 33 + hhl] = bf16_rn(hn);
        }
        __syncthreads();
        // pack h: 4 chunks (j = btl-in-pass, q = k16 half), one per wave
        {
            const int j = wv >> 1, q = wv & 1;
            const int bt   = mblk * 4 + p * 2 + j;
            const int k16h = hhblk * 2 + q;
            union { u16 s[8]; uint4 v; } pk;
            #pragma unroll
            for (int e = 0; e < 8; ++e)
                pk.s[e] = tbuf[(j * 32 + (lane & 31)) * 33
                               + q * 16 + (lane >> 5) * 8 + e];
            *(uint4*)(hpn + ((size_t)bt * 64 + k16h) * 512 + lane * 8) = pk.v;
        }
    }
}

// ---------------------------------------------------------------------------
extern "C" void kernel_launch(void* const* d_in, const int* in_sizes, int n_in,
                              void* d_out, int out_size, void* d_ws, size_t ws_size,
                              hipStream_t stream)
{
    const float* input  = (const float*)d_in[0];
    const float* bridge = (const float*)d_in[1];
    const float* Wih    = (const float*)d_in[2];
    const float* Whh    = (const float*)d_in[3];
    const float* bih    = (const float*)d_in[4];
    const float* bhh    = (const float*)d_in[5];
    float* out = (float*)d_out;

    u16* wp = (u16*)d_ws;
    u16* xp = wp + WPE;
    u16* hp = xp + XPE;
    float* c_buf = (float*)(hp + HPE);
    float* bsum  = c_buf + HPE;

    hipMemsetAsync(hp, 0, (size_t)2 * BH_ * sizeof(u16), stream);
    hipMemsetAsync(c_buf, 0, (size_t)2 * BH_ * sizeof(float), stream);

    bias_sum_k<<<32, 256, 0, stream>>>(bih, bhh, bsum);
    pack_weights<<<8192, 256, 0, stream>>>(Wih, Whh, wp);
    pack_x<<<1920, 256, 0, stream>>>(input, bridge, xp);

    // Wavefront schedule: stage T = cells (node,layer) with depth(node)+layer==T
    static const Stage stages[7] = {
        { {1},                      {0},                      {0},                      1 },
        { {1,2,5,8},                {0,1,1,1},                {1,0,0,0},                4 },
        { {2,5,8,3,6,9,12},         {1,1,1,2,5,8,8},          {1,1,1,0,0,0,0},          7 },
        { {3,6,9,12,4,7,10,13},     {2,5,8,8,3,6,9,12},       {1,1,1,1,0,0,0,0},        8 },
        { {4,7,10,13,11,14},        {3,6,9,12,10,13},         {1,1,1,1,0,0},            6 },
        { {11,14,15},               {10,13,14},               {1,1,0},                  3 },
        { {15},                     {14},                     {1},                      1 },
    };

    for (int s = 0; s < 7; ++s) {
        cell_fused<<<dim3(stages[s].cnt * 64), 256, 0, stream>>>(
            wp, xp, hp, c_buf, bsum, out, stages[s]);
    }
}